// Round 3
// baseline (289.577 us; speedup 1.0000x reference)
//
#include <hip/hip_runtime.h>
#include <hip/hip_bf16.h>

typedef __attribute__((ext_vector_type(8))) short short8;
typedef __attribute__((ext_vector_type(4))) float f32x4;

namespace {
constexpr int kC = 256;
constexpr int kH = 4000;
constexpr int kNW = 800;          // windows per batch
constexpr int kP = 5;
constexpr int kHeads = 8;
constexpr float kScale = 0.17677669529663687f; // 32^-0.5
constexpr int kTotalWin = 32 * kNW;            // 25600

constexpr int WPB = 6;            // windows per block
constexpr int ROWS = WPB * kP;    // 30
constexpr int MT = 2;             // M-tiles of 16 (rows 30,31 junk)
constexpr int NTHR = 512;         // 8 waves

constexpr int WQKV_PACKED = 3 * 16 * 8 * 64 * 8;
constexpr int WOUT_PACKED = 16 * 8 * 64 * 8;

// LDS arena, 45KB -> 3 blocks/CU:
//  region0 [0,15360)      : Xt -> (after GEMM1) q -> (after dots) attn-out
//  regionK [15360,30720)  : k   -> (epilogue) outS f32 [256][30] (spills into V)
//  regionV [30720,46080)  : v
constexpr int RK = 15360;
constexpr int RV = 30720;
constexpr int SM_TOTAL = 46080;
}

__device__ inline float b2f(short s) {
  union { unsigned u; float f; } v;
  v.u = ((unsigned)(unsigned short)s) << 16;
  return v.f;
}
__device__ inline unsigned short f2bs(float f) {
  __hip_bfloat16 h = __float2bfloat16(f);
  return *reinterpret_cast<unsigned short*>(&h);
}

// Pack W_qkv (256x768) / W_out (256x256) f32 -> bf16 MFMA B-fragment order:
// [part][nt][kt][lane][8], B mapping: col = lane&15, k = (lane>>4)*8 + i.
__global__ void prep_weights(const float* __restrict__ Wqkv,
                             const float* __restrict__ Wout,
                             __hip_bfloat16* __restrict__ wq_p,
                             __hip_bfloat16* __restrict__ wo_p) {
  int idx = blockIdx.x * 256 + threadIdx.x;
  if (idx < WQKV_PACKED) {
    int i = idx & 7;
    int l = (idx >> 3) & 63;
    int kt = (idx >> 9) & 7;
    int nt = (idx >> 12) & 15;
    int part = idx >> 16;
    int k = kt * 32 + (l >> 4) * 8 + i;
    int col = part * 256 + nt * 16 + (l & 15);
    wq_p[idx] = __float2bfloat16(Wqkv[k * 768 + col]);
  }
  if (idx < WOUT_PACKED) {
    int i = idx & 7;
    int l = (idx >> 3) & 63;
    int kt = (idx >> 9) & 7;
    int nt = (idx >> 12) & 15;
    int k = kt * 32 + (l >> 4) * 8 + i;
    int col = nt * 16 + (l & 15);
    wo_p[idx] = __float2bfloat16(Wout[k * 256 + col]);
  }
}

__global__ __launch_bounds__(NTHR, 6) void local_attn_kernel(
    const float* __restrict__ x, const short* __restrict__ wq_p,
    const short* __restrict__ wo_p, const float* __restrict__ b_out,
    float* __restrict__ g_out, float* __restrict__ g_attn) {
  __shared__ __align__(16) char smem[SM_TOTAL];

  const int tid = threadIdx.x;
  const int lane = tid & 63;
  const int wid = tid >> 6;

  const int widx0 = blockIdx.x * WPB;
  const int nwin = min(WPB, kTotalWin - widx0);
  const int nrows = nwin * kP;

  // ---- Phase 1: stage Xt (transposed x slice) bf16-swizzled into region0.
  // Pack 2 channels (c = 2cp, 2cp+1) per 4B LDS write.
  for (int i = tid; i < (kC / 2) * ROWS; i += NTHR) {
    int cp = i / ROWS, hh = i % ROWS;
    if (hh < nrows) {
      int gw = widx0 + hh / kP;
      int b = gw / kNW;
      int hl = (gw - b * kNW) * kP + hh % kP;
      const float* p = x + ((size_t)b * kC + 2 * cp) * kH + hl;
      unsigned u = (unsigned)f2bs(p[0]) | ((unsigned)f2bs(p[kH]) << 16);
      *(unsigned*)(smem + hh * 512 + ((cp * 4) ^ ((hh & 7) << 4))) = u;
    }
  }
  __syncthreads();

  // ---- Phase 2: GEMM1 qkv = Xt(32x256) @ Wqkv(256x768)
  // parts k(1), v(2) -> LDS regions; part q(0) kept in regs, then -> region0.
  for (int pi = 0; pi < 2; ++pi) {
    const int part = pi + 1;
    f32x4 acc[MT][2];
#pragma unroll
    for (int m = 0; m < MT; ++m)
#pragma unroll
      for (int n = 0; n < 2; ++n) acc[m][n] = (f32x4){0.f, 0.f, 0.f, 0.f};
#pragma unroll
    for (int kt = 0; kt < 8; ++kt) {
      short8 a[MT];
#pragma unroll
      for (int m = 0; m < MT; ++m) {
        int row = m * 16 + (lane & 15);
        int kb = kt * 64 + ((lane >> 4) << 4);
        a[m] = *(const short8*)(smem + row * 512 + (kb ^ ((row & 7) << 4)));
      }
      short8 b[2];
#pragma unroll
      for (int n = 0; n < 2; ++n) {
        int nt = wid * 2 + n;
        b[n] = *(const short8*)(wq_p +
                                ((((part * 16 + nt) * 8 + kt) * 64 + lane) * 8));
      }
#pragma unroll
      for (int m = 0; m < MT; ++m)
#pragma unroll
        for (int n = 0; n < 2; ++n)
          acc[m][n] = __builtin_amdgcn_mfma_f32_16x16x32_bf16(a[m], b[n],
                                                              acc[m][n], 0, 0, 0);
    }
    char* dst = smem + part * RK;  // part1->RK, part2->RV
#pragma unroll
    for (int m = 0; m < MT; ++m)
#pragma unroll
      for (int n = 0; n < 2; ++n)
#pragma unroll
        for (int r = 0; r < 4; ++r) {
          int row = m * 16 + ((lane >> 4) << 2) + r;
          if (row < ROWS) {
            int col = wid * 32 + n * 16 + (lane & 15);
            *(__hip_bfloat16*)(dst + row * 512 + ((col * 2) ^ ((row & 7) << 4))) =
                __float2bfloat16(acc[m][n][r]);
          }
        }
  }
  // part 0 (q): accumulate in regs while Xt still live
  {
    f32x4 accq[MT][2];
#pragma unroll
    for (int m = 0; m < MT; ++m)
#pragma unroll
      for (int n = 0; n < 2; ++n) accq[m][n] = (f32x4){0.f, 0.f, 0.f, 0.f};
#pragma unroll
    for (int kt = 0; kt < 8; ++kt) {
      short8 a[MT];
#pragma unroll
      for (int m = 0; m < MT; ++m) {
        int row = m * 16 + (lane & 15);
        int kb = kt * 64 + ((lane >> 4) << 4);
        a[m] = *(const short8*)(smem + row * 512 + (kb ^ ((row & 7) << 4)));
      }
      short8 b[2];
#pragma unroll
      for (int n = 0; n < 2; ++n) {
        int nt = wid * 2 + n;
        b[n] = *(const short8*)(wq_p + (((nt * 8 + kt) * 64 + lane) * 8));
      }
#pragma unroll
      for (int m = 0; m < MT; ++m)
#pragma unroll
        for (int n = 0; n < 2; ++n)
          accq[m][n] = __builtin_amdgcn_mfma_f32_16x16x32_bf16(a[m], b[n],
                                                               accq[m][n], 0, 0, 0);
    }
    __syncthreads();  // everyone done reading Xt
#pragma unroll
    for (int m = 0; m < MT; ++m)
#pragma unroll
      for (int n = 0; n < 2; ++n)
#pragma unroll
        for (int r = 0; r < 4; ++r) {
          int row = m * 16 + ((lane >> 4) << 2) + r;
          if (row < ROWS) {
            int col = wid * 32 + n * 16 + (lane & 15);
            *(__hip_bfloat16*)(smem + row * 512 + ((col * 2) ^ ((row & 7) << 4))) =
                __float2bfloat16(accq[m][n][r]);
          }
        }
  }
  __syncthreads();

  // ---- Phase 3: dots + softmax + attn write. task=(w,head,i), half = d-half.
  const int task = tid >> 1, half = tid & 1;
  const bool act = task < nwin * (kHeads * kP);
  float p5[kP];
  int qrow = 0, head = 0, wl = 0, cbase = 0, qsw = 0;
  if (act) {
    wl = task / (kHeads * kP);
    int rem = task % (kHeads * kP);
    head = rem / kP;
    int i = rem % kP;
    qrow = wl * kP + i;
    qsw = (qrow & 7) << 4;
    cbase = head * 64 + half * 32;

    float qf[16];
#pragma unroll
    for (int ch = 0; ch < 2; ++ch) {
      short8 v8 = *(const short8*)(smem + qrow * 512 + ((cbase + ch * 16) ^ qsw));
#pragma unroll
      for (int e = 0; e < 8; ++e) qf[ch * 8 + e] = b2f(v8[e]);
    }
    float mx = -1e30f;
#pragma unroll
    for (int j = 0; j < kP; ++j) {
      int krow = wl * kP + j;
      int ksw = (krow & 7) << 4;
      float s = 0.f;
#pragma unroll
      for (int ch = 0; ch < 2; ++ch) {
        short8 kv =
            *(const short8*)(smem + RK + krow * 512 + ((cbase + ch * 16) ^ ksw));
#pragma unroll
        for (int e = 0; e < 8; ++e) s += qf[ch * 8 + e] * b2f(kv[e]);
      }
      s += __shfl_xor(s, 1);  // combine the two 16-dim halves
      s *= kScale;
      p5[j] = s;
      mx = fmaxf(mx, s);
    }
    float sum = 0.f;
#pragma unroll
    for (int j = 0; j < kP; ++j) {
      p5[j] = __expf(p5[j] - mx);
      sum += p5[j];
    }
    float inv = 1.f / sum;
#pragma unroll
    for (int j = 0; j < kP; ++j) p5[j] *= inv;
    if (!half) {
      float* ap = g_attn + (size_t)(widx0 + wl) * 200 + head * 25 + i * 5;
#pragma unroll
      for (int j = 0; j < kP; ++j) ap[j] = p5[j];
    }
  }
  __syncthreads();  // all q reads done before PV overwrites region0

  // ---- Phase 4: PV -> attn-out into region0 (16 dims per lane)
  if (act) {
    float ov[16];
#pragma unroll
    for (int d = 0; d < 16; ++d) ov[d] = 0.f;
#pragma unroll
    for (int j = 0; j < kP; ++j) {
      float aj = p5[j];
      int vrow = wl * kP + j;
      int vsw = (vrow & 7) << 4;
#pragma unroll
      for (int ch = 0; ch < 2; ++ch) {
        short8 vv =
            *(const short8*)(smem + RV + vrow * 512 + ((cbase + ch * 16) ^ vsw));
#pragma unroll
        for (int e = 0; e < 8; ++e) ov[ch * 8 + e] += aj * b2f(vv[e]);
      }
    }
#pragma unroll
    for (int ch = 0; ch < 2; ++ch) {
      short8 o8;
#pragma unroll
      for (int e = 0; e < 8; ++e) o8[e] = (short)f2bs(ov[ch * 8 + e]);
      *(short8*)(smem + qrow * 512 + ((cbase + ch * 16) ^ qsw)) = o8;
    }
  }
  __syncthreads();

  // ---- Phase 5: GEMM2 out2 = attnout(32x256) @ Wout(256x256) + b_out
  f32x4 acc2[MT][2];
#pragma unroll
  for (int m = 0; m < MT; ++m)
#pragma unroll
    for (int n = 0; n < 2; ++n) acc2[m][n] = (f32x4){0.f, 0.f, 0.f, 0.f};
#pragma unroll
  for (int kt = 0; kt < 8; ++kt) {
    short8 a[MT];
#pragma unroll
    for (int m = 0; m < MT; ++m) {
      int row = m * 16 + (lane & 15);
      int kb = kt * 64 + ((lane >> 4) << 4);
      a[m] = *(const short8*)(smem + row * 512 + (kb ^ ((row & 7) << 4)));
    }
    short8 b[2];
#pragma unroll
    for (int n = 0; n < 2; ++n) {
      int nt = wid * 2 + n;
      b[n] = *(const short8*)(wo_p + (((nt * 8 + kt) * 64 + lane) * 8));
    }
#pragma unroll
    for (int m = 0; m < MT; ++m)
#pragma unroll
      for (int n = 0; n < 2; ++n)
        acc2[m][n] = __builtin_amdgcn_mfma_f32_16x16x32_bf16(a[m], b[n],
                                                             acc2[m][n], 0, 0, 0);
  }
  // epilogue: +bias, stage f32 [256][30] into regionK (k/v dead)
  float* outS = (float*)(smem + RK);
#pragma unroll
  for (int n = 0; n < 2; ++n) {
    int col = wid * 32 + n * 16 + (lane & 15);
    float bias = b_out[col];
#pragma unroll
    for (int m = 0; m < MT; ++m)
#pragma unroll
      for (int r = 0; r < 4; ++r) {
        int row = m * 16 + ((lane >> 4) << 2) + r;
        if (row < ROWS) outS[col * ROWS + row] = acc2[m][n][r] + bias;
      }
  }
  __syncthreads();

  // ---- Phase 6: coalesced-ish writeback out[b][c][h]
  for (int i = tid; i < kC * ROWS; i += NTHR) {
    int c = i / ROWS, hh = i % ROWS;
    if (hh < nrows) {
      int gw = widx0 + hh / kP;
      int b = gw / kNW;
      int hl = (gw - b * kNW) * kP + hh % kP;
      g_out[((size_t)b * kC + c) * kH + hl] = outS[c * ROWS + hh];
    }
  }
}

extern "C" void kernel_launch(void* const* d_in, const int* in_sizes, int n_in,
                              void* d_out, int out_size, void* d_ws,
                              size_t ws_size, hipStream_t stream) {
  const float* x = (const float*)d_in[0];
  const float* Wqkv = (const float*)d_in[1];
  const float* Wout = (const float*)d_in[2];
  const float* bout = (const float*)d_in[3];
  // d_in[4] (pos_embedding) provably cancels in softmax (row-constant bias).

  short* wq_p = (short*)d_ws;
  short* wo_p = wq_p + WQKV_PACKED;

  prep_weights<<<WQKV_PACKED / 256, 256, 0, stream>>>(
      Wqkv, Wout, (__hip_bfloat16*)wq_p, (__hip_bfloat16*)wo_p);

  float* g_out = (float*)d_out;
  float* g_attn = g_out + (size_t)32 * kC * kH;

  int nblocks = (kTotalWin + WPB - 1) / WPB;  // 4267
  local_attn_kernel<<<nblocks, NTHR, 0, stream>>>(x, wq_p, wo_p, bout, g_out,
                                                  g_attn);
}

// Round 4
// 199.439 us; speedup vs baseline: 1.4520x; 1.4520x over previous
//
#include <hip/hip_runtime.h>
#include <hip/hip_bf16.h>

typedef __attribute__((ext_vector_type(8))) short short8;
typedef __attribute__((ext_vector_type(4))) float f32x4;

namespace {
constexpr int kC = 256;
constexpr int kH = 4000;
constexpr int kNW = 800;          // windows per batch
constexpr int kP = 5;
constexpr int kHeads = 8;
constexpr float kScale = 0.17677669529663687f; // 32^-0.5
constexpr int kTotalWin = 32 * kNW;            // 25600

constexpr int WPB = 6;            // windows per block
constexpr int ROWS = WPB * kP;    // 30
constexpr int MT = 2;             // M-tiles of 16 (rows 30,31 junk)
constexpr int NTHR = 512;         // 8 waves

constexpr int WQKV_PACKED = 3 * 16 * 8 * 64 * 8;
constexpr int WOUT_PACKED = 16 * 8 * 64 * 8;

// LDS arena, 45KB -> 3 blocks/CU:
//  region0 [0,15360)      : Xt -> (after GEMM1) q -> (after dots) attn-out
//  regionK [15360,30720)  : k   -> (epilogue) outS f32 [256][30] (spills into V)
//  regionV [30720,46080)  : v
constexpr int RK = 15360;
constexpr int RV = 30720;
constexpr int SM_TOTAL = 46080;
}

__device__ inline float b2f(short s) {
  union { unsigned u; float f; } v;
  v.u = ((unsigned)(unsigned short)s) << 16;
  return v.f;
}
__device__ inline unsigned short f2bs(float f) {
  __hip_bfloat16 h = __float2bfloat16(f);
  return *reinterpret_cast<unsigned short*>(&h);
}

// Pack W_qkv (256x768) / W_out (256x256) f32 -> bf16 MFMA B-fragment order:
// [part][nt][kt][lane][8], B mapping: col = lane&15, k = (lane>>4)*8 + i.
__global__ void prep_weights(const float* __restrict__ Wqkv,
                             const float* __restrict__ Wout,
                             __hip_bfloat16* __restrict__ wq_p,
                             __hip_bfloat16* __restrict__ wo_p) {
  int idx = blockIdx.x * 256 + threadIdx.x;
  if (idx < WQKV_PACKED) {
    int i = idx & 7;
    int l = (idx >> 3) & 63;
    int kt = (idx >> 9) & 7;
    int nt = (idx >> 12) & 15;
    int part = idx >> 16;
    int k = kt * 32 + (l >> 4) * 8 + i;
    int col = part * 256 + nt * 16 + (l & 15);
    wq_p[idx] = __float2bfloat16(Wqkv[k * 768 + col]);
  }
  if (idx < WOUT_PACKED) {
    int i = idx & 7;
    int l = (idx >> 3) & 63;
    int kt = (idx >> 9) & 7;
    int nt = (idx >> 12) & 15;
    int k = kt * 32 + (l >> 4) * 8 + i;
    int col = nt * 16 + (l & 15);
    wo_p[idx] = __float2bfloat16(Wout[k * 256 + col]);
  }
}

// NOTE: __launch_bounds__ arg-2 is CUDA-style min BLOCKS per CU on this
// toolchain (evidence: (512,4)->VGPR 64 cap, (512,6)->VGPR 40 cap + spills).
// 3 blocks/CU matches the 45KB LDS limit; VGPR cap 512/6=85 -> no spills.
__global__ __launch_bounds__(NTHR, 3) void local_attn_kernel(
    const float* __restrict__ x, const short* __restrict__ wq_p,
    const short* __restrict__ wo_p, const float* __restrict__ b_out,
    float* __restrict__ g_out, float* __restrict__ g_attn) {
  __shared__ __align__(16) char smem[SM_TOTAL];

  const int tid = threadIdx.x;
  const int lane = tid & 63;
  const int wid = tid >> 6;

  const int widx0 = blockIdx.x * WPB;
  const int nwin = min(WPB, kTotalWin - widx0);
  const int nrows = nwin * kP;

  // ---- Phase 1: stage Xt (transposed x slice) bf16-swizzled into region0.
  // Pack 2 channels (c = 2cp, 2cp+1) per 4B LDS write.
  for (int i = tid; i < (kC / 2) * ROWS; i += NTHR) {
    int cp = i / ROWS, hh = i % ROWS;
    if (hh < nrows) {
      int gw = widx0 + hh / kP;
      int b = gw / kNW;
      int hl = (gw - b * kNW) * kP + hh % kP;
      const float* p = x + ((size_t)b * kC + 2 * cp) * kH + hl;
      unsigned u = (unsigned)f2bs(p[0]) | ((unsigned)f2bs(p[kH]) << 16);
      *(unsigned*)(smem + hh * 512 + ((cp * 4) ^ ((hh & 7) << 4))) = u;
    }
  }
  __syncthreads();

  // ---- Phase 2: GEMM1 qkv = Xt(32x256) @ Wqkv(256x768)
  // parts k(1), v(2) -> LDS regions; part q(0) kept in regs, then -> region0.
  for (int pi = 0; pi < 2; ++pi) {
    const int part = pi + 1;
    f32x4 acc[MT][2];
#pragma unroll
    for (int m = 0; m < MT; ++m)
#pragma unroll
      for (int n = 0; n < 2; ++n) acc[m][n] = (f32x4){0.f, 0.f, 0.f, 0.f};
#pragma unroll
    for (int kt = 0; kt < 8; ++kt) {
      short8 a[MT];
#pragma unroll
      for (int m = 0; m < MT; ++m) {
        int row = m * 16 + (lane & 15);
        int kb = kt * 64 + ((lane >> 4) << 4);
        a[m] = *(const short8*)(smem + row * 512 + (kb ^ ((row & 7) << 4)));
      }
      short8 b[2];
#pragma unroll
      for (int n = 0; n < 2; ++n) {
        int nt = wid * 2 + n;
        b[n] = *(const short8*)(wq_p +
                                ((((part * 16 + nt) * 8 + kt) * 64 + lane) * 8));
      }
#pragma unroll
      for (int m = 0; m < MT; ++m)
#pragma unroll
        for (int n = 0; n < 2; ++n)
          acc[m][n] = __builtin_amdgcn_mfma_f32_16x16x32_bf16(a[m], b[n],
                                                              acc[m][n], 0, 0, 0);
    }
    char* dst = smem + part * RK;  // part1->RK, part2->RV
#pragma unroll
    for (int m = 0; m < MT; ++m)
#pragma unroll
      for (int n = 0; n < 2; ++n)
#pragma unroll
        for (int r = 0; r < 4; ++r) {
          int row = m * 16 + ((lane >> 4) << 2) + r;
          if (row < ROWS) {
            int col = wid * 32 + n * 16 + (lane & 15);
            *(__hip_bfloat16*)(dst + row * 512 + ((col * 2) ^ ((row & 7) << 4))) =
                __float2bfloat16(acc[m][n][r]);
          }
        }
  }
  // part 0 (q): accumulate in regs while Xt still live
  {
    f32x4 accq[MT][2];
#pragma unroll
    for (int m = 0; m < MT; ++m)
#pragma unroll
      for (int n = 0; n < 2; ++n) accq[m][n] = (f32x4){0.f, 0.f, 0.f, 0.f};
#pragma unroll
    for (int kt = 0; kt < 8; ++kt) {
      short8 a[MT];
#pragma unroll
      for (int m = 0; m < MT; ++m) {
        int row = m * 16 + (lane & 15);
        int kb = kt * 64 + ((lane >> 4) << 4);
        a[m] = *(const short8*)(smem + row * 512 + (kb ^ ((row & 7) << 4)));
      }
      short8 b[2];
#pragma unroll
      for (int n = 0; n < 2; ++n) {
        int nt = wid * 2 + n;
        b[n] = *(const short8*)(wq_p + (((nt * 8 + kt) * 64 + lane) * 8));
      }
#pragma unroll
      for (int m = 0; m < MT; ++m)
#pragma unroll
        for (int n = 0; n < 2; ++n)
          accq[m][n] = __builtin_amdgcn_mfma_f32_16x16x32_bf16(a[m], b[n],
                                                               accq[m][n], 0, 0, 0);
    }
    __syncthreads();  // everyone done reading Xt
#pragma unroll
    for (int m = 0; m < MT; ++m)
#pragma unroll
      for (int n = 0; n < 2; ++n)
#pragma unroll
        for (int r = 0; r < 4; ++r) {
          int row = m * 16 + ((lane >> 4) << 2) + r;
          if (row < ROWS) {
            int col = wid * 32 + n * 16 + (lane & 15);
            *(__hip_bfloat16*)(smem + row * 512 + ((col * 2) ^ ((row & 7) << 4))) =
                __float2bfloat16(accq[m][n][r]);
          }
        }
  }
  __syncthreads();

  // ---- Phase 3: dots + softmax + attn write. task=(w,head,i), half = d-half.
  const int task = tid >> 1, half = tid & 1;
  const bool act = task < nwin * (kHeads * kP);
  float p5[kP];
  int qrow = 0, head = 0, wl = 0, cbase = 0, qsw = 0;
  if (act) {
    wl = task / (kHeads * kP);
    int rem = task % (kHeads * kP);
    head = rem / kP;
    int i = rem % kP;
    qrow = wl * kP + i;
    qsw = (qrow & 7) << 4;
    cbase = head * 64 + half * 32;

    float qf[16];
#pragma unroll
    for (int ch = 0; ch < 2; ++ch) {
      short8 v8 = *(const short8*)(smem + qrow * 512 + ((cbase + ch * 16) ^ qsw));
#pragma unroll
      for (int e = 0; e < 8; ++e) qf[ch * 8 + e] = b2f(v8[e]);
    }
    float mx = -1e30f;
#pragma unroll
    for (int j = 0; j < kP; ++j) {
      int krow = wl * kP + j;
      int ksw = (krow & 7) << 4;
      float s = 0.f;
#pragma unroll
      for (int ch = 0; ch < 2; ++ch) {
        short8 kv =
            *(const short8*)(smem + RK + krow * 512 + ((cbase + ch * 16) ^ ksw));
#pragma unroll
        for (int e = 0; e < 8; ++e) s += qf[ch * 8 + e] * b2f(kv[e]);
      }
      s += __shfl_xor(s, 1);  // combine the two 16-dim halves
      s *= kScale;
      p5[j] = s;
      mx = fmaxf(mx, s);
    }
    float sum = 0.f;
#pragma unroll
    for (int j = 0; j < kP; ++j) {
      p5[j] = __expf(p5[j] - mx);
      sum += p5[j];
    }
    float inv = 1.f / sum;
#pragma unroll
    for (int j = 0; j < kP; ++j) p5[j] *= inv;
    if (!half) {
      float* ap = g_attn + (size_t)(widx0 + wl) * 200 + head * 25 + i * 5;
#pragma unroll
      for (int j = 0; j < kP; ++j) ap[j] = p5[j];
    }
  }
  __syncthreads();  // all q reads done before PV overwrites region0

  // ---- Phase 4: PV -> attn-out into region0 (16 dims per lane)
  if (act) {
    float ov[16];
#pragma unroll
    for (int d = 0; d < 16; ++d) ov[d] = 0.f;
#pragma unroll
    for (int j = 0; j < kP; ++j) {
      float aj = p5[j];
      int vrow = wl * kP + j;
      int vsw = (vrow & 7) << 4;
#pragma unroll
      for (int ch = 0; ch < 2; ++ch) {
        short8 vv =
            *(const short8*)(smem + RV + vrow * 512 + ((cbase + ch * 16) ^ vsw));
#pragma unroll
        for (int e = 0; e < 8; ++e) ov[ch * 8 + e] += aj * b2f(vv[e]);
      }
    }
#pragma unroll
    for (int ch = 0; ch < 2; ++ch) {
      short8 o8;
#pragma unroll
      for (int e = 0; e < 8; ++e) o8[e] = (short)f2bs(ov[ch * 8 + e]);
      *(short8*)(smem + qrow * 512 + ((cbase + ch * 16) ^ qsw)) = o8;
    }
  }
  __syncthreads();

  // ---- Phase 5: GEMM2 out2 = attnout(32x256) @ Wout(256x256) + b_out
  f32x4 acc2[MT][2];
#pragma unroll
  for (int m = 0; m < MT; ++m)
#pragma unroll
    for (int n = 0; n < 2; ++n) acc2[m][n] = (f32x4){0.f, 0.f, 0.f, 0.f};
#pragma unroll
  for (int kt = 0; kt < 8; ++kt) {
    short8 a[MT];
#pragma unroll
    for (int m = 0; m < MT; ++m) {
      int row = m * 16 + (lane & 15);
      int kb = kt * 64 + ((lane >> 4) << 4);
      a[m] = *(const short8*)(smem + row * 512 + (kb ^ ((row & 7) << 4)));
    }
    short8 b[2];
#pragma unroll
    for (int n = 0; n < 2; ++n) {
      int nt = wid * 2 + n;
      b[n] = *(const short8*)(wo_p + (((nt * 8 + kt) * 64 + lane) * 8));
    }
#pragma unroll
    for (int m = 0; m < MT; ++m)
#pragma unroll
      for (int n = 0; n < 2; ++n)
        acc2[m][n] = __builtin_amdgcn_mfma_f32_16x16x32_bf16(a[m], b[n],
                                                             acc2[m][n], 0, 0, 0);
  }
  // epilogue: +bias, stage f32 [256][30] into regionK (k/v dead)
  float* outS = (float*)(smem + RK);
#pragma unroll
  for (int n = 0; n < 2; ++n) {
    int col = wid * 32 + n * 16 + (lane & 15);
    float bias = b_out[col];
#pragma unroll
    for (int m = 0; m < MT; ++m)
#pragma unroll
      for (int r = 0; r < 4; ++r) {
        int row = m * 16 + ((lane >> 4) << 2) + r;
        if (row < ROWS) outS[col * ROWS + row] = acc2[m][n][r] + bias;
      }
  }
  __syncthreads();

  // ---- Phase 6: coalesced-ish writeback out[b][c][h]
  for (int i = tid; i < kC * ROWS; i += NTHR) {
    int c = i / ROWS, hh = i % ROWS;
    if (hh < nrows) {
      int gw = widx0 + hh / kP;
      int b = gw / kNW;
      int hl = (gw - b * kNW) * kP + hh % kP;
      g_out[((size_t)b * kC + c) * kH + hl] = outS[c * ROWS + hh];
    }
  }
}

extern "C" void kernel_launch(void* const* d_in, const int* in_sizes, int n_in,
                              void* d_out, int out_size, void* d_ws,
                              size_t ws_size, hipStream_t stream) {
  const float* x = (const float*)d_in[0];
  const float* Wqkv = (const float*)d_in[1];
  const float* Wout = (const float*)d_in[2];
  const float* bout = (const float*)d_in[3];
  // d_in[4] (pos_embedding) provably cancels in softmax (row-constant bias).

  short* wq_p = (short*)d_ws;
  short* wo_p = wq_p + WQKV_PACKED;

  prep_weights<<<WQKV_PACKED / 256, 256, 0, stream>>>(
      Wqkv, Wout, (__hip_bfloat16*)wq_p, (__hip_bfloat16*)wo_p);

  float* g_out = (float*)d_out;
  float* g_attn = g_out + (size_t)32 * kC * kH;

  int nblocks = (kTotalWin + WPB - 1) / WPB;  // 4267
  local_attn_kernel<<<nblocks, NTHR, 0, stream>>>(x, wq_p, wo_p, bout, g_out,
                                                  g_attn);
}

// Round 5
// 191.524 us; speedup vs baseline: 1.5120x; 1.0413x over previous
//
#include <hip/hip_runtime.h>
#include <hip/hip_bf16.h>

typedef __attribute__((ext_vector_type(8))) short short8;
typedef __attribute__((ext_vector_type(4))) float f32x4;

namespace {
constexpr int kC = 256;
constexpr int kH = 4000;
constexpr int kNW = 800;          // windows per batch
constexpr int kP = 5;
constexpr float kScale = 0.17677669529663687f; // 32^-0.5
constexpr int kTotalWin = 25600;

constexpr int WPB = 6;            // windows per block
constexpr int ROWS = WPB * kP;    // 30
constexpr int MT = 2;             // M-tiles of 16 (rows 30,31 junk)
constexpr int NTHR = 512;         // 8 waves; wave == head for attention

constexpr int WQKV_PACKED = 3 * 16 * 8 * 64 * 8;
constexpr int WOUT_PACKED = 16 * 8 * 64 * 8;

// LDS arena, 46KB -> 3 blocks/CU:
//  R0  [0,15360)       : Xt -> q -> attn-out   (30 rows x 512B, row-XOR swz)
//  RK  [15360,30720)   : k (30x512B) -> S5/P region [head8][qrow30][64B] -> outS (w/ RVT)
//  RVT [30720,47104)   : Vt [head8][d32][64B], chunk-XOR swz; ks slots 30,31 zeroed
constexpr int RKOFF = 15360;
constexpr int RVT = 30720;
constexpr int SM_TOTAL = 47104;
}

__device__ inline float b2f(short s) {
  union { unsigned u; float f; } v;
  v.u = ((unsigned)(unsigned short)s) << 16;
  return v.f;
}
__device__ inline unsigned short f2bs(float f) {
  __hip_bfloat16 h = __float2bfloat16(f);
  return *reinterpret_cast<unsigned short*>(&h);
}

// Pack W_qkv (256x768) / W_out (256x256) f32 -> bf16 MFMA B-fragment order:
// [part][nt][kt][lane][8], B mapping: col = lane&15, k = (lane>>4)*8 + i.
__global__ void prep_weights(const float* __restrict__ Wqkv,
                             const float* __restrict__ Wout,
                             __hip_bfloat16* __restrict__ wq_p,
                             __hip_bfloat16* __restrict__ wo_p) {
  int idx = blockIdx.x * 256 + threadIdx.x;
  if (idx < WQKV_PACKED) {
    int i = idx & 7;
    int l = (idx >> 3) & 63;
    int kt = (idx >> 9) & 7;
    int nt = (idx >> 12) & 15;
    int part = idx >> 16;
    int k = kt * 32 + (l >> 4) * 8 + i;
    int col = part * 256 + nt * 16 + (l & 15);
    wq_p[idx] = __float2bfloat16(Wqkv[k * 768 + col]);
  }
  if (idx < WOUT_PACKED) {
    int i = idx & 7;
    int l = (idx >> 3) & 63;
    int kt = (idx >> 9) & 7;
    int nt = (idx >> 12) & 15;
    int k = kt * 32 + (l >> 4) * 8 + i;
    int col = nt * 16 + (l & 15);
    wo_p[idx] = __float2bfloat16(Wout[k * 256 + col]);
  }
}

// launch_bounds arg2 behaves as CUDA-style min BLOCKS/CU here:
// (512,4)->VGPR64, (512,6)->VGPR40+spills, (512,3)->VGPR60 no spills.
__global__ __launch_bounds__(NTHR, 3) void local_attn_kernel(
    const float* __restrict__ x, const short* __restrict__ wq_p,
    const short* __restrict__ wo_p, const float* __restrict__ b_out,
    float* __restrict__ g_out, float* __restrict__ g_attn) {
  __shared__ __align__(16) char smem[SM_TOTAL];

  const int tid = threadIdx.x;
  const int lane = tid & 63;
  const int wid = tid >> 6;

  const int widx0 = blockIdx.x * WPB;
  const int nwin = min(WPB, kTotalWin - widx0);
  const int nrows = nwin * kP;

  // ---- P1: stage Xt bf16-swizzled into R0 (2 channels per 4B write);
  //          zero Vt key-slots 30,31 (MFMA K=32 tail).
  for (int i = tid; i < (kC / 2) * ROWS; i += NTHR) {
    int cp = i / ROWS, hh = i % ROWS;
    if (hh < nrows) {
      int gw = widx0 + hh / kP;
      int b = gw / kNW;
      int hl = (gw - b * kNW) * kP + hh % kP;
      const float* p = x + ((size_t)b * kC + 2 * cp) * kH + hl;
      unsigned u = (unsigned)f2bs(p[0]) | ((unsigned)f2bs(p[kH]) << 16);
      *(unsigned*)(smem + hh * 512 + ((cp * 4) ^ ((hh & 7) << 4))) = u;
    }
  }
  if (tid < 256) {
    int h = tid >> 5, d = tid & 31;
    int phys = 3 ^ ((d >> 1) & 3);  // logical chunk 3 (bytes 48..63)
    *(unsigned*)(smem + RVT + h * 2048 + d * 64 + phys * 16 + 12) = 0u;
  }
  __syncthreads();

  // ---- P2: GEMM1 qkv = Xt(32x256) @ Wqkv. k -> RK rows; v -> Vt transposed;
  //          q in regs -> R0 after Xt dead.
  for (int pi = 0; pi < 2; ++pi) {
    const int part = pi + 1;
    f32x4 acc[MT][2];
#pragma unroll
    for (int m = 0; m < MT; ++m)
#pragma unroll
      for (int n = 0; n < 2; ++n) acc[m][n] = (f32x4){0.f, 0.f, 0.f, 0.f};
#pragma unroll
    for (int kt = 0; kt < 8; ++kt) {
      short8 a[MT];
#pragma unroll
      for (int m = 0; m < MT; ++m) {
        int row = m * 16 + (lane & 15);
        int kb = kt * 64 + ((lane >> 4) << 4);
        a[m] = *(const short8*)(smem + row * 512 + (kb ^ ((row & 7) << 4)));
      }
      short8 b[2];
#pragma unroll
      for (int n = 0; n < 2; ++n) {
        int nt = wid * 2 + n;
        b[n] = *(const short8*)(wq_p +
                                ((((part * 16 + nt) * 8 + kt) * 64 + lane) * 8));
      }
#pragma unroll
      for (int m = 0; m < MT; ++m)
#pragma unroll
        for (int n = 0; n < 2; ++n)
          acc[m][n] = __builtin_amdgcn_mfma_f32_16x16x32_bf16(a[m], b[n],
                                                              acc[m][n], 0, 0, 0);
    }
    if (part == 1) {  // k -> RK [row][col] swizzled
#pragma unroll
      for (int m = 0; m < MT; ++m)
#pragma unroll
        for (int n = 0; n < 2; ++n)
#pragma unroll
          for (int r = 0; r < 4; ++r) {
            int row = m * 16 + ((lane >> 4) << 2) + r;
            if (row < ROWS) {
              int col = wid * 32 + n * 16 + (lane & 15);
              *(__hip_bfloat16*)(smem + RKOFF + row * 512 +
                                 ((col * 2) ^ ((row & 7) << 4))) =
                  __float2bfloat16(acc[m][n][r]);
            }
          }
    } else {  // v -> Vt[head=wid][d][ks], chunk-swizzled
#pragma unroll
      for (int m = 0; m < MT; ++m)
#pragma unroll
        for (int n = 0; n < 2; ++n)
#pragma unroll
          for (int r = 0; r < 4; ++r) {
            int ks = m * 16 + ((lane >> 4) << 2) + r;
            if (ks < ROWS) {
              int d = n * 16 + (lane & 15);
              int lb = ks * 2;
              int phys = (lb >> 4) ^ ((d >> 1) & 3);
              *(__hip_bfloat16*)(smem + RVT + wid * 2048 + d * 64 + phys * 16 +
                                 (lb & 15)) = __float2bfloat16(acc[m][n][r]);
            }
          }
    }
  }
  {  // part 0 (q) in regs while Xt still live
    f32x4 accq[MT][2];
#pragma unroll
    for (int m = 0; m < MT; ++m)
#pragma unroll
      for (int n = 0; n < 2; ++n) accq[m][n] = (f32x4){0.f, 0.f, 0.f, 0.f};
#pragma unroll
    for (int kt = 0; kt < 8; ++kt) {
      short8 a[MT];
#pragma unroll
      for (int m = 0; m < MT; ++m) {
        int row = m * 16 + (lane & 15);
        int kb = kt * 64 + ((lane >> 4) << 4);
        a[m] = *(const short8*)(smem + row * 512 + (kb ^ ((row & 7) << 4)));
      }
      short8 b[2];
#pragma unroll
      for (int n = 0; n < 2; ++n) {
        int nt = wid * 2 + n;
        b[n] = *(const short8*)(wq_p + (((nt * 8 + kt) * 64 + lane) * 8));
      }
#pragma unroll
      for (int m = 0; m < MT; ++m)
#pragma unroll
        for (int n = 0; n < 2; ++n)
          accq[m][n] = __builtin_amdgcn_mfma_f32_16x16x32_bf16(a[m], b[n],
                                                               accq[m][n], 0, 0, 0);
    }
    __syncthreads();  // B2: Xt reads done
#pragma unroll
    for (int m = 0; m < MT; ++m)
#pragma unroll
      for (int n = 0; n < 2; ++n)
#pragma unroll
        for (int r = 0; r < 4; ++r) {
          int row = m * 16 + ((lane >> 4) << 2) + r;
          if (row < ROWS) {
            int col = wid * 32 + n * 16 + (lane & 15);
            *(__hip_bfloat16*)(smem + row * 512 + ((col * 2) ^ ((row & 7) << 4))) =
                __float2bfloat16(accq[m][n][r]);
          }
        }
  }
  __syncthreads();  // B3: q/k/Vt visible

  // ---- P3: QK^T via MFMA. wave = head. S = q(30x32) @ k^T -> 2x2 tiles K=32.
  f32x4 sacc[2][2];
  {
    short8 qa[2], kb2[2];
#pragma unroll
    for (int mt = 0; mt < 2; ++mt) {
      int row = mt * 16 + (lane & 15);
      qa[mt] = *(const short8*)(smem + row * 512 +
                                ((wid * 64 + ((lane >> 4) << 4)) ^ ((row & 7) << 4)));
    }
#pragma unroll
    for (int nt = 0; nt < 2; ++nt) {
      int row = nt * 16 + (lane & 15);
      kb2[nt] = *(const short8*)(smem + RKOFF + row * 512 +
                                 ((wid * 64 + ((lane >> 4) << 4)) ^ ((row & 7) << 4)));
    }
#pragma unroll
    for (int mt = 0; mt < 2; ++mt)
#pragma unroll
      for (int nt = 0; nt < 2; ++nt)
        sacc[mt][nt] = __builtin_amdgcn_mfma_f32_16x16x32_bf16(
            qa[mt], kb2[nt], (f32x4){0.f, 0.f, 0.f, 0.f}, 0, 0, 0);
  }
  __syncthreads();  // B4: all k reads done; S5 may now overwrite RK region

  // S5 scores -> P region rows (bytes 0..19, chunk-swizzled), same-window only
#pragma unroll
  for (int mt = 0; mt < 2; ++mt)
#pragma unroll
    for (int nt = 0; nt < 2; ++nt)
#pragma unroll
      for (int r = 0; r < 4; ++r) {
        int qrow = mt * 16 + ((lane >> 4) << 2) + r;
        int krow = nt * 16 + (lane & 15);
        int qw = qrow / 5, kw = krow / 5;
        if (qrow < ROWS && krow < ROWS && qw == kw) {
          int jj = (krow - kw * 5) * 4;
          int phys = (((jj >> 4) ^ ((qrow >> 1) & 3)) << 4) | (jj & 15);
          *(float*)(smem + RKOFF + wid * 1920 + qrow * 64 + phys) =
              sacc[mt][nt][r] * kScale;
        }
      }
  __syncthreads();  // B5: S5 written

  // ---- P4: softmax. 240 tasks = (head, qrow). Read S5, write attn + P row.
  if (tid < 240) {
    int q = tid % 30, h = tid / 30;
    int w = q / 5, i = q - w * 5;
    if (w < nwin) {
      char* base = smem + RKOFF + h * 1920 + q * 64;
      int csw = (q >> 1) & 3;
      float p[5], mx = -1e30f;
#pragma unroll
      for (int j = 0; j < 5; ++j) {
        int jj = j * 4;
        p[j] = *(const float*)(base + ((((jj >> 4) ^ csw) << 4) | (jj & 15)));
        mx = fmaxf(mx, p[j]);
      }
      float sum = 0.f;
#pragma unroll
      for (int j = 0; j < 5; ++j) {
        p[j] = __expf(p[j] - mx);
        sum += p[j];
      }
      float inv = 1.f / sum;
      float* ap = g_attn + (size_t)(widx0 + w) * 200 + h * 25 + i * 5;
#pragma unroll
      for (int j = 0; j < 5; ++j) {
        p[j] *= inv;
        ap[j] = p[j];
      }
      short8 z = (short8){0, 0, 0, 0, 0, 0, 0, 0};
#pragma unroll
      for (int c = 0; c < 4; ++c) *(short8*)(base + c * 16) = z;
#pragma unroll
      for (int j = 0; j < 5; ++j) {
        int lb = (w * 5 + j) * 2;
        *(unsigned short*)(base + ((((lb >> 4) ^ csw) << 4) | (lb & 15))) =
            f2bs(p[j]);
      }
    }
  }
  __syncthreads();  // B6: P rows ready

  // ---- P5: PV via MFMA: out^T = Vt(32x30) @ P^T -> attn-out into R0
  {
    short8 va[2], pb[2];
#pragma unroll
    for (int mt = 0; mt < 2; ++mt) {
      int d = mt * 16 + (lane & 15);
      int phys = ((lane >> 4) ^ ((d >> 1) & 3)) << 4;
      va[mt] = *(const short8*)(smem + RVT + wid * 2048 + d * 64 + phys);
    }
#pragma unroll
    for (int nt = 0; nt < 2; ++nt) {
      int q = nt * 16 + (lane & 15);
      int phys = ((lane >> 4) ^ ((q >> 1) & 3)) << 4;
      pb[nt] = *(const short8*)(smem + RKOFF + wid * 1920 + q * 64 + phys);
    }
#pragma unroll
    for (int mt = 0; mt < 2; ++mt)
#pragma unroll
      for (int nt = 0; nt < 2; ++nt) {
        f32x4 o = __builtin_amdgcn_mfma_f32_16x16x32_bf16(
            va[mt], pb[nt], (f32x4){0.f, 0.f, 0.f, 0.f}, 0, 0, 0);
#pragma unroll
        for (int r = 0; r < 4; ++r) {
          int d = mt * 16 + ((lane >> 4) << 2) + r;
          int q = nt * 16 + (lane & 15);
          if (q < ROWS) {
            int cb = wid * 64 + d * 2;
            *(__hip_bfloat16*)(smem + q * 512 + (cb ^ ((q & 7) << 4))) =
                __float2bfloat16(o[r]);
          }
        }
      }
  }
  __syncthreads();  // B7: attn-out ready

  // ---- P6: GEMM2 out2 = attnout(32x256) @ Wout + b_out
  f32x4 acc2[MT][2];
#pragma unroll
  for (int m = 0; m < MT; ++m)
#pragma unroll
    for (int n = 0; n < 2; ++n) acc2[m][n] = (f32x4){0.f, 0.f, 0.f, 0.f};
#pragma unroll
  for (int kt = 0; kt < 8; ++kt) {
    short8 a[MT];
#pragma unroll
    for (int m = 0; m < MT; ++m) {
      int row = m * 16 + (lane & 15);
      int kb = kt * 64 + ((lane >> 4) << 4);
      a[m] = *(const short8*)(smem + row * 512 + (kb ^ ((row & 7) << 4)));
    }
    short8 b[2];
#pragma unroll
    for (int n = 0; n < 2; ++n) {
      int nt = wid * 2 + n;
      b[n] = *(const short8*)(wo_p + (((nt * 8 + kt) * 64 + lane) * 8));
    }
#pragma unroll
    for (int m = 0; m < MT; ++m)
#pragma unroll
      for (int n = 0; n < 2; ++n)
        acc2[m][n] = __builtin_amdgcn_mfma_f32_16x16x32_bf16(a[m], b[n],
                                                             acc2[m][n], 0, 0, 0);
  }
  // epilogue: +bias, stage f32 [256][30] at RKOFF (P/Vt dead)
  float* outS = (float*)(smem + RKOFF);
#pragma unroll
  for (int n = 0; n < 2; ++n) {
    int col = wid * 32 + n * 16 + (lane & 15);
    float bias = b_out[col];
#pragma unroll
    for (int m = 0; m < MT; ++m)
#pragma unroll
      for (int r = 0; r < 4; ++r) {
        int row = m * 16 + ((lane >> 4) << 2) + r;
        if (row < ROWS) outS[col * ROWS + row] = acc2[m][n][r] + bias;
      }
  }
  __syncthreads();  // B8

  // ---- P7: writeback out[b][c][h]
  for (int i = tid; i < kC * ROWS; i += NTHR) {
    int c = i / ROWS, hh = i % ROWS;
    if (hh < nrows) {
      int gw = widx0 + hh / kP;
      int b = gw / kNW;
      int hl = (gw - b * kNW) * kP + hh % kP;
      g_out[((size_t)b * kC + c) * kH + hl] = outS[c * ROWS + hh];
    }
  }
}

extern "C" void kernel_launch(void* const* d_in, const int* in_sizes, int n_in,
                              void* d_out, int out_size, void* d_ws,
                              size_t ws_size, hipStream_t stream) {
  const float* x = (const float*)d_in[0];
  const float* Wqkv = (const float*)d_in[1];
  const float* Wout = (const float*)d_in[2];
  const float* bout = (const float*)d_in[3];
  // d_in[4] (pos_embedding) provably cancels in softmax (row-constant bias).

  short* wq_p = (short*)d_ws;
  short* wo_p = wq_p + WQKV_PACKED;

  prep_weights<<<WQKV_PACKED / 256, 256, 0, stream>>>(
      Wqkv, Wout, (__hip_bfloat16*)wq_p, (__hip_bfloat16*)wo_p);

  float* g_out = (float*)d_out;
  float* g_attn = g_out + (size_t)32 * kC * kH;

  int nblocks = (kTotalWin + WPB - 1) / WPB;  // 4267
  local_attn_kernel<<<nblocks, NTHR, 0, stream>>>(x, wq_p, wo_p, bout, g_out,
                                                  g_attn);
}